// Round 2
// baseline (8760.675 us; speedup 1.0000x reference)
//
#include <hip/hip_runtime.h>
#include <stdint.h>

#define B_  128
#define T_  1024
#define H_  512
#define I_  64
#define TB_ 131072   // T_*B_

typedef _Float16 half2_t __attribute__((ext_vector_type(2)));

union U32H2 { uint32_t u; half2_t h; };
union U16H  { uint16_t u; _Float16 h; };

static __device__ __forceinline__ half2_t u2h(uint32_t u){ U32H2 x; x.u=u; return x.h; }
static __device__ __forceinline__ uint32_t h2u(half2_t h){ U32H2 x; x.h=h; return x.u; }

#if defined(__has_builtin)
#if __has_builtin(__builtin_amdgcn_fdot2)
#define HAVE_FDOT2 1
#endif
#endif

static __device__ __forceinline__ float fdot2f(half2_t a, half2_t b, float c){
#ifdef HAVE_FDOT2
    return __builtin_amdgcn_fdot2(a, b, c, false);
#else
    return c + (float)a[0]*(float)b[0] + (float)a[1]*(float)b[1];
#endif
}

// LDS-visibility-only barrier (no vmcnt drain).
#define BARRIER_NODRAIN() do {                                        \
    __asm__ __volatile__("s_waitcnt lgkmcnt(0)" ::: "memory");        \
    __builtin_amdgcn_s_barrier();                                     \
    __asm__ __volatile__("" ::: "memory");                            \
} while (0)

// ---------------------------------------------------------------------------
// Kernel A (fused): r[t*128+b][j] = f16( sum_i x[b][t][i]*W_in[j][i] + sigma[j][t*128+b] )
// grid (8, 1024): blockIdx.x = j-group (so the 8 blocks sharing one t-tile of x
// dispatch adjacently -> L2 reuse), blockIdx.y = t. block 256.
// Pad 68 (mult of 4): LDS reads in the i-loop become b128.
// ---------------------------------------------------------------------------
__global__ __launch_bounds__(256) void k_wingemm(const float* __restrict__ x,
                                                 const float* __restrict__ Win,
                                                 const float* __restrict__ sigma,
                                                 uint32_t* __restrict__ r2)
{
    __shared__ float As[128*68];   // [b][i]; reused as Sg[64][130] after the GEMM
    __shared__ float Ws[64*68];    // [j][i]
    const int t   = blockIdx.y;
    const int j0  = blockIdx.x * 64;
    const int tid = threadIdx.x;

    // stage x[b][t][0:64] -> As[b][:]
#pragma unroll
    for (int k = 0; k < 8; k++){
        int qid = k*256 + tid;           // [0,2048)
        int row = qid >> 4;              // b
        int qq  = qid & 15;
        float4 v = *(const float4*)(x + ((size_t)row*T_ + t)*I_ + qq*4);
        *(float4*)(As + row*68 + qq*4) = v;
    }
    // stage W_in[j0+r][0:64] -> Ws[r][:]
#pragma unroll
    for (int k = 0; k < 4; k++){
        int qid = k*256 + tid;           // [0,1024)
        int row = qid >> 4;
        int qq  = qid & 15;
        float4 v = *(const float4*)(Win + (size_t)(j0+row)*I_ + qq*4);
        *(float4*)(Ws + row*68 + qq*4) = v;
    }
    __syncthreads();

    const int tj = tid & 15;   // j-pair group (fast-varying lane dim -> coalesced stores)
    const int tb = tid >> 4;   // [0,16)

    float acc[8][2][2];
#pragma unroll
    for (int bb=0; bb<8; bb++)
#pragma unroll
        for (int jj=0; jj<2; jj++){ acc[bb][jj][0]=0.f; acc[bb][jj][1]=0.f; }

#pragma unroll 4
    for (int iq = 0; iq < 16; iq++){
        float4 w00 = *(const float4*)(Ws + (2*tj     )*68 + iq*4);
        float4 w01 = *(const float4*)(Ws + (2*tj + 1 )*68 + iq*4);
        float4 w10 = *(const float4*)(Ws + (2*tj + 32)*68 + iq*4);
        float4 w11 = *(const float4*)(Ws + (2*tj + 33)*68 + iq*4);
#pragma unroll
        for (int bb=0; bb<8; bb++){
            float4 a = *(const float4*)(As + (tb + 16*bb)*68 + iq*4);
            // sequential i-order preserved (bitwise-identical accumulation)
            acc[bb][0][0] += a.x*w00.x; acc[bb][0][0] += a.y*w00.y;
            acc[bb][0][0] += a.z*w00.z; acc[bb][0][0] += a.w*w00.w;
            acc[bb][0][1] += a.x*w01.x; acc[bb][0][1] += a.y*w01.y;
            acc[bb][0][1] += a.z*w01.z; acc[bb][0][1] += a.w*w01.w;
            acc[bb][1][0] += a.x*w10.x; acc[bb][1][0] += a.y*w10.y;
            acc[bb][1][0] += a.z*w10.z; acc[bb][1][0] += a.w*w10.w;
            acc[bb][1][1] += a.x*w11.x; acc[bb][1][1] += a.y*w11.y;
            acc[bb][1][1] += a.z*w11.z; acc[bb][1][1] += a.w*w11.w;
        }
    }
    __syncthreads();   // all As reads done; safe to overwrite with sigma tile

    // stage sigma[j0+row][t*128 + 0:128] -> Sg[row][0:128] (pad 130)
    float* Sg = As;
#pragma unroll
    for (int k = 0; k < 8; k++){
        int qid = k*256 + tid;           // [0,2048): 64 rows x 32 float4
        int row = qid >> 5;
        int qq  = qid & 31;
        float4 v = *(const float4*)(sigma + (size_t)(j0+row)*TB_ + (size_t)t*128 + qq*4);
        *(float4*)(Sg + row*130 + qq*4) = v;
    }
    __syncthreads();

#pragma unroll
    for (int bb=0; bb<8; bb++){
        int bcol = tb + 16*bb;
        int mi = t*128 + bcol;
#pragma unroll
        for (int jj=0; jj<2; jj++){
            int jA = 2*tj + 32*jj;
            float a0 = acc[bb][jj][0] + Sg[(jA    )*130 + bcol];
            float a1 = acc[bb][jj][1] + Sg[(jA + 1)*130 + bcol];
            half2_t hv; hv[0]=(_Float16)a0; hv[1]=(_Float16)a1;
            r2[(size_t)mi*256 + (j0>>1) + tj + 16*jj] = h2u(hv);
        }
    }
}

// ---------------------------------------------------------------------------
// Kernel B: the recurrence. One workgroup per batch column b. 512 threads.
// Thread t = (wave w, lane l): k-chunk [64w,64w+64); rows {l+64m, m<8}.
// W f16: rows m<7 in 224 VGPR-pairs, row 7 in LDS (rotated, conflict-free b128).
// s = sigmoid(h): wave w's k-chunk == its own lanes' j-range -> sb write/read is
// INTRA-WAVE, needs no barrier (lgkmcnt ordering only).
// par double-buffered -> ONE nodrain barrier per step.
// ---------------------------------------------------------------------------
#define RNN_STEP(PAR, TS) {                                                   \
    uint16_t ru = 0;                                                          \
    if (USE_R) ru = rp[(size_t)(TS) << 16];                                   \
    float e = __expf(-h);                                                     \
    float s = 1.0f / (1.0f + e);                                              \
    sb[j] = (_Float16)s;                                                      \
    float p[8];                                                               \
    _Pragma("unroll") for (int m = 0; m < 8; m++) p[m] = 0.f;                 \
    _Pragma("unroll") for (int c = 0; c < 8; c++){                            \
        uint4 sq = *(const uint4*)(sbu + (w << 5) + (c << 2));                \
        half2_t s0=u2h(sq.x), s1=u2h(sq.y), s2=u2h(sq.z), s3=u2h(sq.w);       \
        uint4 q7 = *(const uint4*)(WLt + ((4*c + ph) & 31));                  \
        _Pragma("unroll") for (int m = 0; m < 7; m++){                        \
            p[m] = fdot2f(wreg[m][4*c+0], s0, p[m]);                          \
            p[m] = fdot2f(wreg[m][4*c+1], s1, p[m]);                          \
            p[m] = fdot2f(wreg[m][4*c+2], s2, p[m]);                          \
            p[m] = fdot2f(wreg[m][4*c+3], s3, p[m]);                          \
        }                                                                     \
        p[7] = fdot2f(u2h(q7.x), s0, p[7]);                                   \
        p[7] = fdot2f(u2h(q7.y), s1, p[7]);                                   \
        p[7] = fdot2f(u2h(q7.z), s2, p[7]);                                   \
        p[7] = fdot2f(u2h(q7.w), s3, p[7]);                                   \
    }                                                                         \
    _Pragma("unroll") for (int m = 0; m < 8; m++)                             \
        PAR[(l + (m << 6))*9 + w] = p[m];                                     \
    BARRIER_NODRAIN();                                                        \
    const float* pj = PAR + j*9;                                              \
    float P = ((pj[0] + pj[1]) + (pj[2] + pj[3]))                             \
            + ((pj[4] + pj[5]) + (pj[6] + pj[7]));                            \
    float rv;                                                                 \
    if (USE_R){ U16H cv; cv.u = ru; rv = (float)cv.h; }                       \
    else {                                                                    \
        float acc = 0.f;                                                      \
        const float4* wir = (const float4*)(Win + (size_t)j*I_);              \
        const float4* xr  = (const float4*)(x + ((size_t)b*T_ + (TS))*I_);    \
        _Pragma("unroll") for (int q = 0; q < 16; q++){                       \
            float4 a = wir[q]; float4 xx = xr[q];                             \
            acc += a.x*xx.x + a.y*xx.y + a.z*xx.z + a.w*xx.w;                 \
        }                                                                     \
        rv = acc + sigma[((size_t)j << 17) + ((TS) << 7) + b];                \
    }                                                                         \
    h = 0.9f*h + 0.1f*(P + rv);                                               \
    outp[(size_t)(TS) * H_] = h;                                              \
}

template<int USE_R>
__global__ __launch_bounds__(512, 2) void k_rnn(const float* __restrict__ Wh,
                                                const float* __restrict__ Win,
                                                const float* __restrict__ x,
                                                const float* __restrict__ sigma,
                                                const float* __restrict__ h0,
                                                const uint16_t* __restrict__ r16,
                                                float* __restrict__ out)
{
    extern __shared__ char smem[];
    uint32_t*  WL   = (uint32_t*)smem;                        // [512*32] u32, 64 KB (W row m=7, rotated)
    float*     parA = (float*)(smem + 65536);                 // [512*9] floats
    float*     parB = (float*)(smem + 65536 + 18432);         // [512*9] floats
    _Float16*  sb   = (_Float16*)(smem + 65536 + 36864);      // [512]

    const int b = blockIdx.x;
    const int t = threadIdx.x;
    const int w = t >> 6;
    const int l = t & 63;
    const int j = t;
    const int ph = (l & 7) << 2;   // rotation in u32-pairs, mult of 4 -> b128 aligned

    // one-time: load W_hidden slice, convert fp32 -> f16 pairs
    half2_t wreg[7][32];
#pragma unroll
    for (int m = 0; m < 8; m++){
        const float4* wr = (const float4*)(Wh + (size_t)(l + 64*m)*H_ + (w << 6));
#pragma unroll 2
        for (int q = 0; q < 16; q++){
            float4 v = wr[q];
            half2_t a; a[0]=(_Float16)v.x; a[1]=(_Float16)v.y;
            half2_t c; c[0]=(_Float16)v.z; c[1]=(_Float16)v.w;
            int pp = 2*q;
            if (m < 7){
                wreg[m][pp]   = a;
                wreg[m][pp+1] = c;
            } else {
                WL[t*32 + ((pp     + ph) & 31)] = h2u(a);
                WL[t*32 + ((pp + 1 + ph) & 31)] = h2u(c);
            }
        }
    }

    float h = h0[(size_t)j*B_ + b];
    const uint32_t* WLt = WL + t*32;
    const uint32_t* sbu = (const uint32_t*)sb;
    float* outp = out + (size_t)b*T_*H_ + j;
    const uint16_t* rp = r16 + (size_t)b*H_ + j;   // element (ts*128+b)*512 + j

    for (int ts = 0; ts < T_; ts += 2){
        RNN_STEP(parA, ts);
        RNN_STEP(parB, ts + 1);
    }

    // h_last[j][b]
    out[(size_t)B_*T_*H_ + (size_t)j*B_ + b] = h;
}

// ---------------------------------------------------------------------------
extern "C" void kernel_launch(void* const* d_in, const int* in_sizes, int n_in,
                              void* d_out, int out_size, void* d_ws, size_t ws_size,
                              hipStream_t stream)
{
    const float* x     = (const float*)d_in[0];
    const float* Win   = (const float*)d_in[1];
    const float* Wh    = (const float*)d_in[2];
    const float* sigma = (const float*)d_in[3];
    const float* h0    = (const float*)d_in[4];
    float* out = (float*)d_out;

    const size_t r_bytes = (size_t)TB_ * H_ * 2;   // 134,217,728 B (f16 r)
    const int use_r = (ws_size >= r_bytes) ? 1 : 0;

    const int lds_bytes = 65536 + 2*18432 + 1024;  // 103,424

    if (use_r){
        k_wingemm<<<dim3(8, T_), 256, 0, stream>>>(x, Win, sigma, (uint32_t*)d_ws);
        (void)hipFuncSetAttribute((const void*)(k_rnn<1>),
                                  hipFuncAttributeMaxDynamicSharedMemorySize, lds_bytes);
        k_rnn<1><<<B_, 512, lds_bytes, stream>>>(Wh, Win, x, sigma, h0,
                                                 (const uint16_t*)d_ws, out);
    } else {
        (void)hipFuncSetAttribute((const void*)(k_rnn<0>),
                                  hipFuncAttributeMaxDynamicSharedMemorySize, lds_bytes);
        k_rnn<0><<<B_, 512, lds_bytes, stream>>>(Wh, Win, x, sigma, h0,
                                                 (const uint16_t*)d_ws, out);
    }
}

// Round 3
// 6942.205 us; speedup vs baseline: 1.2619x; 1.2619x over previous
//
#include <hip/hip_runtime.h>
#include <stdint.h>

#define B_  128
#define T_  1024
#define H_  512
#define I_  64
#define TB_ 131072   // T_*B_

typedef _Float16 half2_t __attribute__((ext_vector_type(2)));

union U32H2 { uint32_t u; half2_t h; };
union U16H  { uint16_t u; _Float16 h; };

static __device__ __forceinline__ half2_t u2h(uint32_t u){ U32H2 x; x.u=u; return x.h; }
static __device__ __forceinline__ uint32_t h2u(half2_t h){ U32H2 x; x.h=h; return x.u; }

#if defined(__has_builtin)
#if __has_builtin(__builtin_amdgcn_fdot2)
#define HAVE_FDOT2 1
#endif
#endif

static __device__ __forceinline__ float fdot2f(half2_t a, half2_t b, float c){
#ifdef HAVE_FDOT2
    return __builtin_amdgcn_fdot2(a, b, c, false);
#else
    return c + (float)a[0]*(float)b[0] + (float)a[1]*(float)b[1];
#endif
}

// LDS-visibility-only barrier (no vmcnt drain).
#define BARRIER_NODRAIN() do {                                        \
    __asm__ __volatile__("s_waitcnt lgkmcnt(0)" ::: "memory");        \
    __builtin_amdgcn_s_barrier();                                     \
    __asm__ __volatile__("" ::: "memory");                            \
} while (0)

// ---------------------------------------------------------------------------
// Kernel A (fused): r[t*128+b][j] = f16( sum_i x[b][t][i]*W_in[j][i] + sigma[j][t*128+b] )
// grid (8, 1024), block 256. Unchanged from round 2 (verified).
// ---------------------------------------------------------------------------
__global__ __launch_bounds__(256) void k_wingemm(const float* __restrict__ x,
                                                 const float* __restrict__ Win,
                                                 const float* __restrict__ sigma,
                                                 uint32_t* __restrict__ r2)
{
    __shared__ float As[128*68];   // [b][i]; reused as Sg[64][130] after the GEMM
    __shared__ float Ws[64*68];    // [j][i]
    const int t   = blockIdx.y;
    const int j0  = blockIdx.x * 64;
    const int tid = threadIdx.x;

#pragma unroll
    for (int k = 0; k < 8; k++){
        int qid = k*256 + tid;
        int row = qid >> 4;
        int qq  = qid & 15;
        float4 v = *(const float4*)(x + ((size_t)row*T_ + t)*I_ + qq*4);
        *(float4*)(As + row*68 + qq*4) = v;
    }
#pragma unroll
    for (int k = 0; k < 4; k++){
        int qid = k*256 + tid;
        int row = qid >> 4;
        int qq  = qid & 15;
        float4 v = *(const float4*)(Win + (size_t)(j0+row)*I_ + qq*4);
        *(float4*)(Ws + row*68 + qq*4) = v;
    }
    __syncthreads();

    const int tj = tid & 15;
    const int tb = tid >> 4;

    float acc[8][2][2];
#pragma unroll
    for (int bb=0; bb<8; bb++)
#pragma unroll
        for (int jj=0; jj<2; jj++){ acc[bb][jj][0]=0.f; acc[bb][jj][1]=0.f; }

#pragma unroll 4
    for (int iq = 0; iq < 16; iq++){
        float4 w00 = *(const float4*)(Ws + (2*tj     )*68 + iq*4);
        float4 w01 = *(const float4*)(Ws + (2*tj + 1 )*68 + iq*4);
        float4 w10 = *(const float4*)(Ws + (2*tj + 32)*68 + iq*4);
        float4 w11 = *(const float4*)(Ws + (2*tj + 33)*68 + iq*4);
#pragma unroll
        for (int bb=0; bb<8; bb++){
            float4 a = *(const float4*)(As + (tb + 16*bb)*68 + iq*4);
            acc[bb][0][0] += a.x*w00.x; acc[bb][0][0] += a.y*w00.y;
            acc[bb][0][0] += a.z*w00.z; acc[bb][0][0] += a.w*w00.w;
            acc[bb][0][1] += a.x*w01.x; acc[bb][0][1] += a.y*w01.y;
            acc[bb][0][1] += a.z*w01.z; acc[bb][0][1] += a.w*w01.w;
            acc[bb][1][0] += a.x*w10.x; acc[bb][1][0] += a.y*w10.y;
            acc[bb][1][0] += a.z*w10.z; acc[bb][1][0] += a.w*w10.w;
            acc[bb][1][1] += a.x*w11.x; acc[bb][1][1] += a.y*w11.y;
            acc[bb][1][1] += a.z*w11.z; acc[bb][1][1] += a.w*w11.w;
        }
    }
    __syncthreads();

    float* Sg = As;
#pragma unroll
    for (int k = 0; k < 8; k++){
        int qid = k*256 + tid;
        int row = qid >> 5;
        int qq  = qid & 31;
        float4 v = *(const float4*)(sigma + (size_t)(j0+row)*TB_ + (size_t)t*128 + qq*4);
        *(float4*)(Sg + row*130 + qq*4) = v;
    }
    __syncthreads();

#pragma unroll
    for (int bb=0; bb<8; bb++){
        int bcol = tb + 16*bb;
        int mi = t*128 + bcol;
#pragma unroll
        for (int jj=0; jj<2; jj++){
            int jA = 2*tj + 32*jj;
            float a0 = acc[bb][jj][0] + Sg[(jA    )*130 + bcol];
            float a1 = acc[bb][jj][1] + Sg[(jA + 1)*130 + bcol];
            half2_t hv; hv[0]=(_Float16)a0; hv[1]=(_Float16)a1;
            r2[(size_t)mi*256 + (j0>>1) + tj + 16*jj] = h2u(hv);
        }
    }
}

// ---------------------------------------------------------------------------
// Kernel B: 256 threads / 4 waves per block, one block per batch column b.
// 1 wave/SIMD, __launch_bounds__(256,1) -> 512 VGPR/wave budget.
// Wave w's k-chunk: [64w,64w+64) U [256+64w,256+64w+64)  (dual 64-chunk so the
//   sigmoid values it consumes are written by its OWN lanes -> intra-wave, no barrier).
// Lane l computes partials for rows {l+64m, m=0..7}; thread t owns h[t], h[t+256].
// W f16: rows m<6 in 384 VGPRs (wreg[6][64]); rows 6,7 in LDS, rotated b128.
// One nodrain barrier per step; par double-buffered (stride 5: 4 waves + pad).
// ---------------------------------------------------------------------------
#define RNN_STEP(PAR, TS) {                                                     \
    uint16_t ru1 = 0, ru2 = 0;                                                  \
    if (USE_R){ ru1 = rp1[(size_t)(TS) << 16];                                  \
                ru2 = rp1[((size_t)(TS) << 16) + 256]; }                        \
    float e1 = __expf(-h1), e2 = __expf(-h2);                                   \
    float s1 = 1.0f/(1.0f+e1), s2 = 1.0f/(1.0f+e2);                             \
    sb[t]     = (_Float16)s1;                                                   \
    sb[t+256] = (_Float16)s2;                                                   \
    float p[8];                                                                 \
    _Pragma("unroll") for (int m = 0; m < 8; m++) p[m] = 0.f;                   \
    _Pragma("unroll") for (int c = 0; c < 16; c++){                             \
        uint4 sq = *(const uint4*)(sbu + swbase + 4*c + ((c>=8)?96:0));         \
        half2_t s0=u2h(sq.x), sA=u2h(sq.y), sB=u2h(sq.z), sC=u2h(sq.w);         \
        uint4 q6 = *(const uint4*)(WLt + (((4*c) + ph) & 63));                  \
        uint4 q7 = *(const uint4*)(WLt + 64 + (((4*c) + ph) & 63));             \
        _Pragma("unroll") for (int m = 0; m < 6; m++){                          \
            p[m] = fdot2f(wreg[m][4*c+0], s0, p[m]);                            \
            p[m] = fdot2f(wreg[m][4*c+1], sA, p[m]);                            \
            p[m] = fdot2f(wreg[m][4*c+2], sB, p[m]);                            \
            p[m] = fdot2f(wreg[m][4*c+3], sC, p[m]);                            \
        }                                                                       \
        p[6] = fdot2f(u2h(q6.x), s0, p[6]); p[6] = fdot2f(u2h(q6.y), sA, p[6]); \
        p[6] = fdot2f(u2h(q6.z), sB, p[6]); p[6] = fdot2f(u2h(q6.w), sC, p[6]); \
        p[7] = fdot2f(u2h(q7.x), s0, p[7]); p[7] = fdot2f(u2h(q7.y), sA, p[7]); \
        p[7] = fdot2f(u2h(q7.z), sB, p[7]); p[7] = fdot2f(u2h(q7.w), sC, p[7]); \
    }                                                                           \
    _Pragma("unroll") for (int m = 0; m < 8; m++)                               \
        PAR[(l + (m << 6))*5 + w] = p[m];                                       \
    BARRIER_NODRAIN();                                                          \
    {                                                                           \
        const float* pj1 = PAR + t*5;                                           \
        const float* pj2 = PAR + (t+256)*5;                                     \
        float P1 = (pj1[0] + pj1[1]) + (pj1[2] + pj1[3]);                       \
        float P2 = (pj2[0] + pj2[1]) + (pj2[2] + pj2[3]);                       \
        float rv1, rv2;                                                         \
        if (USE_R){                                                             \
            U16H c1; c1.u = ru1; rv1 = (float)c1.h;                             \
            U16H c2; c2.u = ru2; rv2 = (float)c2.h;                             \
        } else {                                                                \
            float a1c = 0.f, a2c = 0.f;                                         \
            const float4* w1r = (const float4*)(Win + (size_t)t*I_);            \
            const float4* w2r = (const float4*)(Win + (size_t)(t+256)*I_);      \
            const float4* xr  = (const float4*)(x + ((size_t)b*T_ + (TS))*I_);  \
            _Pragma("unroll") for (int q = 0; q < 16; q++){                     \
                float4 xx = xr[q];                                              \
                float4 aa = w1r[q]; float4 bb = w2r[q];                         \
                a1c += aa.x*xx.x + aa.y*xx.y + aa.z*xx.z + aa.w*xx.w;           \
                a2c += bb.x*xx.x + bb.y*xx.y + bb.z*xx.z + bb.w*xx.w;           \
            }                                                                   \
            rv1 = a1c + sigma[((size_t)t << 17) + ((TS) << 7) + b];             \
            rv2 = a2c + sigma[((size_t)(t+256) << 17) + ((TS) << 7) + b];       \
        }                                                                       \
        h1 = 0.9f*h1 + 0.1f*(P1 + rv1);                                         \
        h2 = 0.9f*h2 + 0.1f*(P2 + rv2);                                         \
        outp1[(size_t)(TS) * H_]       = h1;                                    \
        outp1[(size_t)(TS) * H_ + 256] = h2;                                    \
    }                                                                           \
}

template<int USE_R>
__global__ __launch_bounds__(256, 1) void k_rnn(const float* __restrict__ Wh,
                                                const float* __restrict__ Win,
                                                const float* __restrict__ x,
                                                const float* __restrict__ sigma,
                                                const float* __restrict__ h0,
                                                const uint16_t* __restrict__ r16,
                                                float* __restrict__ out)
{
    extern __shared__ char smem[];
    uint32_t*  WL   = (uint32_t*)smem;                    // [256*128] u32, 128 KB (rows 6,7)
    float*     parA = (float*)(smem + 131072);            // [512*5] floats, 10240 B
    float*     parB = (float*)(smem + 141312);            // [512*5] floats, 10240 B
    _Float16*  sb   = (_Float16*)(smem + 151552);         // [512], 1 KB

    const int b = blockIdx.x;
    const int t = threadIdx.x;      // [0,256)
    const int w = t >> 6;           // wave [0,4)
    const int l = t & 63;
    const int ph = (l & 15) << 2;   // rotation within 64-word row region, b128-aligned
    const int swbase = w << 5;      // sb u32 base for chunk A

    // one-time: W_hidden slice -> f16. Lane l, rows {l+64m}; k in dual chunk.
    // word index u in [0,64): u<32 -> k = 64w + 2u..; u>=32 -> k = 256+64w + 2(u-32)..
    half2_t wreg[6][64];
#pragma unroll
    for (int m = 0; m < 8; m++){
        const float* wrow = Wh + (size_t)(l + 64*m)*H_;
#pragma unroll
        for (int hf = 0; hf < 2; hf++){
            const float4* wr = (const float4*)(wrow + hf*256 + (w << 6));
#pragma unroll
            for (int q4 = 0; q4 < 16; q4++){
                float4 v = wr[q4];
                half2_t a; a[0]=(_Float16)v.x; a[1]=(_Float16)v.y;
                half2_t c; c[0]=(_Float16)v.z; c[1]=(_Float16)v.w;
                int pp = hf*32 + 2*q4;
                if (m < 6){
                    wreg[m][pp]   = a;
                    wreg[m][pp+1] = c;
                } else {
                    int ro = (m-6)*64;
                    WL[t*128 + ro + ((pp     + ph) & 63)] = h2u(a);
                    WL[t*128 + ro + ((pp + 1 + ph) & 63)] = h2u(c);
                }
            }
        }
    }

    float h1 = h0[(size_t)t*B_ + b];
    float h2 = h0[(size_t)(t+256)*B_ + b];
    const uint32_t* WLt = WL + t*128;
    const uint32_t* sbu = (const uint32_t*)sb;
    float* outp1 = out + (size_t)b*T_*H_ + t;
    const uint16_t* rp1 = r16 + (size_t)b*H_ + t;   // element (ts*128+b)*512 + t

#pragma unroll 1
    for (int ts = 0; ts < T_; ts += 2){
        RNN_STEP(parA, ts);
        RNN_STEP(parB, ts + 1);
    }

    // h_last[j][b]
    out[(size_t)B_*T_*H_ + (size_t)t*B_ + b]       = h1;
    out[(size_t)B_*T_*H_ + (size_t)(t+256)*B_ + b] = h2;
}

// ---------------------------------------------------------------------------
extern "C" void kernel_launch(void* const* d_in, const int* in_sizes, int n_in,
                              void* d_out, int out_size, void* d_ws, size_t ws_size,
                              hipStream_t stream)
{
    const float* x     = (const float*)d_in[0];
    const float* Win   = (const float*)d_in[1];
    const float* Wh    = (const float*)d_in[2];
    const float* sigma = (const float*)d_in[3];
    const float* h0    = (const float*)d_in[4];
    float* out = (float*)d_out;

    const size_t r_bytes = (size_t)TB_ * H_ * 2;   // 134,217,728 B (f16 r)
    const int use_r = (ws_size >= r_bytes) ? 1 : 0;

    const int lds_bytes = 131072 + 2*10240 + 1024;  // 152,576

    if (use_r){
        k_wingemm<<<dim3(8, T_), 256, 0, stream>>>(x, Win, sigma, (uint32_t*)d_ws);
        (void)hipFuncSetAttribute((const void*)(k_rnn<1>),
                                  hipFuncAttributeMaxDynamicSharedMemorySize, lds_bytes);
        k_rnn<1><<<B_, 256, lds_bytes, stream>>>(Wh, Win, x, sigma, h0,
                                                 (const uint16_t*)d_ws, out);
    } else {
        (void)hipFuncSetAttribute((const void*)(k_rnn<0>),
                                  hipFuncAttributeMaxDynamicSharedMemorySize, lds_bytes);
        k_rnn<0><<<B_, 256, lds_bytes, stream>>>(Wh, Win, x, sigma, h0,
                                                 (const uint16_t*)d_ws, out);
    }
}